// Round 10
// baseline (48.469 us; speedup 1.0000x reference)
//
#include <hip/hip_runtime.h>
#include <hip/hip_bf16.h>

// ---------------------------------------------------------------------------
// scores[y,x] = sum_h W2[h] * ( sum_{m,n} leaky( py[y,h,m,:].px[x,h,n,:] /8 ) ) / (nItem[x]*64)
// 2 nodes (node-count slope measured ~3.5us/node; in-kernel sync worse: r5/r7):
//   k_prep3 (336 blk, r9 geometry + in-block weight scatter, no wprep node):
//     px 144 blk (32 x-rows): w1f+wpq scatter-built from W1/Wp; GEMM1 full-K
//       in regs via 16KB LDS quarters; gelu -> gal; GEMM2 -> pxf frags.
//     py 192 blk (32 y-rows): w1f scatter; GEMM2 -> pyf frags.
//   k_att (768 blk = 24 yb x 32 xq) — r6 verbatim: wave = 1 yi x 3 xi,
//     A-frags register-resident, B prefetch-pipelined, leaky in epilogue FMAs.
// Fragment map (A and B of mfma_f32_16x16x32_bf16, same map):
//   lane l holds (rc=l&15, k=8*(l>>4)+i), i=0..7.  C/D: col=l&15, row=(l>>4)*4+j.
// py image: [y][h][mt(4)][kc(2)][lane(64)][i(8)]
// px image: [x][h][nt(3)][kc(2)][lane(64)][i(8)]
// ---------------------------------------------------------------------------

typedef short bf16x8 __attribute__((ext_vector_type(8)));
typedef float f32x4 __attribute__((ext_vector_type(4)));

__device__ __forceinline__ unsigned short f2bf(float v) {
  __hip_bfloat16 b = __float2bfloat16(v);
  return *reinterpret_cast<unsigned short*>(&b);
}

__device__ __forceinline__ bf16x8 load8_cvt(const float* __restrict__ p) {
  f32x4 v0 = *reinterpret_cast<const f32x4*>(p);
  f32x4 v1 = *reinterpret_cast<const f32x4*>(p + 4);
  bf16x8 r;
  r[0] = (short)f2bf(v0[0]); r[1] = (short)f2bf(v0[1]);
  r[2] = (short)f2bf(v0[2]); r[3] = (short)f2bf(v0[3]);
  r[4] = (short)f2bf(v1[0]); r[5] = (short)f2bf(v1[1]);
  r[6] = (short)f2bf(v1[2]); r[7] = (short)f2bf(v1[3]);
  return r;
}

// ---------------------------------------------------------------------------
// node1: px+py frag production, weights scatter-built in-block.
// LDS: w1f 16KB | wpq 16KB (quarter) | gal 4.5KB = 36.5KB.
// ---------------------------------------------------------------------------
__global__ __launch_bounds__(256, 3) void k_prep3(const float* __restrict__ x,
                                                  const float* __restrict__ y,
                                                  const float* __restrict__ Wp,
                                                  const float* __restrict__ W1,
                                                  unsigned short* __restrict__ pyf,
                                                  unsigned short* __restrict__ pxf) {
  __shared__ unsigned short w1f[8192];     // [kc2][nt8][lane][8]
  __shared__ unsigned short wpq[8192];     // quarter: [kcl4][nt4][lane][8]
  __shared__ unsigned short gal[32 * 72];  // padded gallery tile
  int t = threadIdx.x;
  int lane = t & 63, w = t >> 6;
  int b = blockIdx.x;

  const bf16x8* WF = reinterpret_cast<const bf16x8*>(w1f);
  const bf16x8* WPQ = reinterpret_cast<const bf16x8*>(wpq);

  // w1f scatter-build (both block types)
#pragma unroll
  for (int it = 0; it < 32; ++it) {
    int idx = it * 256 + t;                // over 64*128
    int k = idx >> 7, d = idx & 127;
    int l = (d & 15) + 16 * ((k >> 3) & 3);
    int f = (k >> 5) * 8 + (d >> 4);
    w1f[f * 512 + l * 8 + (k & 7)] = f2bf(W1[idx]);
  }

  f32x4 zero4 = {0.f, 0.f, 0.f, 0.f};
  asm volatile("" : "+v"(zero4));          // pin zero C-operand

  if (b < 144) {
    // =========================== px: 32 x-rows ===========================
    int rowbase = b * 32;
    int rt = w & 1, ntp = (w >> 1) * 2;
    const float* xa = x + (size_t)(rowbase + rt * 16 + (lane & 15)) * 512 + 8 * (lane >> 4);
    f32x4 acc[2] = {{0, 0, 0, 0}, {0, 0, 0, 0}};
#pragma unroll
    for (int q = 0; q < 4; ++q) {          // K quarters of 128
      if (q) __syncthreads();              // prev quarter's reads done
#pragma unroll
      for (int it = 0; it < 32; ++it) {    // scatter-build quarter from Wp
        int idx = it * 256 + t;            // over 128*64
        int kq = idx >> 6, c = idx & 63;
        int l = (c & 15) + 16 * ((kq >> 3) & 3);
        int g = ((kq >> 5) & 3) * 4 + (c >> 4);
        wpq[g * 512 + l * 8 + (kq & 7)] = f2bf(Wp[(q * 128 + kq) * 64 + c]);
      }
      __syncthreads();                     // quarter staged (first also covers w1f)
#pragma unroll
      for (int kk = 0; kk < 4; ++kk) {
        bf16x8 a = load8_cvt(xa + 32 * (q * 4 + kk));
#pragma unroll
        for (int u = 0; u < 2; ++u)
          acc[u] = __builtin_amdgcn_mfma_f32_16x16x32_bf16(a, WPQ[(kk * 4 + ntp + u) * 64 + lane], acc[u], 0, 0, 0);
      }
    }
    // gelu -> gal (each wave owns distinct (rt, ntp) cells)
#pragma unroll
    for (int u = 0; u < 2; ++u)
#pragma unroll
      for (int j = 0; j < 4; ++j) {
        float s = acc[u][j];
        float ge = 0.5f * s * (1.0f + erff(s * 0.70710678118654752f));
        int lr = rt * 16 + (lane >> 4) * 4 + j;
        int c = (ntp + u) * 16 + (lane & 15);
        gal[lr * 72 + c] = f2bf(ge);
      }
    __syncthreads();
    // GEMM2: wave w -> row-tile rt, nt2 = nb..nb+3
    int nb = (w >> 1) * 4;
    const unsigned short* gp = &gal[(rt * 16 + (lane & 15)) * 72 + 8 * (lane >> 4)];
    bf16x8 g0 = *reinterpret_cast<const bf16x8*>(gp);
    bf16x8 g1 = *reinterpret_cast<const bf16x8*>(gp + 32);
#pragma unroll
    for (int v = 0; v < 4; ++v) {
      int nt2 = nb + v;
      f32x4 acc2 = __builtin_amdgcn_mfma_f32_16x16x32_bf16(g0, WF[nt2 * 64 + lane], zero4, 0, 0, 0);
      acc2 = __builtin_amdgcn_mfma_f32_16x16x32_bf16(g1, WF[(8 + nt2) * 64 + lane], acc2, 0, 0, 0);
      int d = nt2 * 16 + (lane & 15);
      int h = d >> 6, dd = d & 63;
      int kc = dd >> 5, q2 = (dd >> 3) & 3, i = dd & 7;
#pragma unroll
      for (int j = 0; j < 4; ++j) {
        int row = rowbase + rt * 16 + (lane >> 4) * 4 + j;
        int xi = row / 48, n = row % 48;
        int nt3 = n >> 4, rr = n & 15;
        size_t idx = ((size_t)((xi * 2 + h) * 6 + nt3 * 2 + kc)) * 512 + (rr + (q2 << 4)) * 8 + i;
        pxf[idx] = f2bf(acc2[j]);
      }
    }
  } else {
    // =========================== py: 32 y-rows ===========================
    __syncthreads();                       // w1f staged
    int b2 = b - 144;
    int mt = w & 1, nb = (w >> 1) * 4;
    const float* ybp = y + (size_t)(b2 * 32 + mt * 16 + (lane & 15)) * 64 + 8 * (lane >> 4);
    bf16x8 a0 = load8_cvt(ybp);
    bf16x8 a1 = load8_cvt(ybp + 32);
#pragma unroll
    for (int v = 0; v < 4; ++v) {
      int nt2 = nb + v;
      f32x4 acc = __builtin_amdgcn_mfma_f32_16x16x32_bf16(a0, WF[nt2 * 64 + lane], zero4, 0, 0, 0);
      acc = __builtin_amdgcn_mfma_f32_16x16x32_bf16(a1, WF[(8 + nt2) * 64 + lane], acc, 0, 0, 0);
      int d = nt2 * 16 + (lane & 15);
      int h = d >> 6, dd = d & 63;
      int kc = dd >> 5, q2 = (dd >> 3) & 3, i = dd & 7;
#pragma unroll
      for (int j = 0; j < 4; ++j) {
        int row = b2 * 32 + mt * 16 + (lane >> 4) * 4 + j;
        int yi = row >> 6, m = row & 63;
        int mt3 = m >> 4, rr = m & 15;
        size_t idx = ((size_t)((yi * 2 + h) * 8 + mt3 * 2 + kc)) * 512 + (rr + (q2 << 4)) * 8 + i;
        pyf[idx] = f2bf(acc[j]);
      }
    }
  }
}

// ---------------------------------------------------------------------------
// node2: pairwise att (r6 verbatim — the control). 768 blocks.
// ---------------------------------------------------------------------------
__global__ __launch_bounds__(256) void k_att(const unsigned short* __restrict__ pyf_u,
                                             const unsigned short* __restrict__ pxf_u,
                                             const float* __restrict__ nItem,
                                             const float* __restrict__ W2,
                                             float* __restrict__ out) {
  int lane = threadIdx.x & 63;
  int w = threadIdx.x >> 6;
  int bid = blockIdx.x;
  int yb = bid >> 5, xq = bid & 31;
  int yi = yb * 4 + w;
  int xi0 = xq * 3;
  const bf16x8* PA = reinterpret_cast<const bf16x8*>(pyf_u);
  const bf16x8* PB = reinterpret_cast<const bf16x8*>(pxf_u);

  float w2h0 = W2[0], w2h1 = W2[1];
  float nI0 = nItem[xi0], nI1 = nItem[xi0 + 1], nI2 = nItem[xi0 + 2];

  f32x4 zero4 = {0.f, 0.f, 0.f, 0.f};
  asm volatile("" : "+v"(zero4));

  bf16x8 A8[16];                           // both heads: [h*8 + mt*2 + kc]
  size_t abase = (size_t)(yi * 2) * 512 + lane;
#pragma unroll
  for (int f = 0; f < 8; ++f) {
    A8[f]     = PA[abase + f * 64];
    A8[8 + f] = PA[abase + 512 + f * 64];
  }
  float c3h0 = 0.3f * w2h0, c7h0 = 0.7f * w2h0;
  float c3h1 = 0.3f * w2h1, c7h1 = 0.7f * w2h1;

  bf16x8 Bc[6], Bn[6];
  size_t bb0 = (size_t)((xi0 * 2 + 0) * 6) * 64 + lane;  // s=0: g=0,h=0
#pragma unroll
  for (int f = 0; f < 6; ++f) Bc[f] = PB[bb0 + f * 64];

  f32x4 res4[3];
#pragma unroll
  for (int g = 0; g < 3; ++g) res4[g] = (f32x4){0.f, 0.f, 0.f, 0.f};

#pragma unroll
  for (int s = 0; s < 6; ++s) {
    const int h = s / 3, g = s % 3;
    if (s < 5) {                            // prefetch next step's B-frags
      const int s2 = s + 1, h2 = s2 / 3, g2 = s2 % 3;
      size_t bb = (size_t)(((xi0 + g2) * 2 + h2) * 6) * 64 + lane;
#pragma unroll
      for (int f = 0; f < 6; ++f) Bn[f] = PB[bb + f * 64];
    }
    const float c3 = h ? c3h1 : c3h0;
    const float c7 = h ? c7h1 : c7h0;
#pragma unroll
    for (int nt = 0; nt < 3; ++nt)
#pragma unroll
      for (int mt = 0; mt < 4; ++mt) {
        f32x4 acc = __builtin_amdgcn_mfma_f32_16x16x32_bf16(A8[h * 8 + mt * 2], Bc[nt * 2], zero4, 0, 0, 0);
        acc = __builtin_amdgcn_mfma_f32_16x16x32_bf16(A8[h * 8 + mt * 2 + 1], Bc[nt * 2 + 1], acc, 0, 0, 0);
        f32x4 mx = {fmaxf(acc[0], 0.f), fmaxf(acc[1], 0.f), fmaxf(acc[2], 0.f), fmaxf(acc[3], 0.f)};
        res4[g] += acc * c3;
        res4[g] += mx * c7;
      }
#pragma unroll
    for (int f = 0; f < 6; ++f) Bc[f] = Bn[f];  // renamed away by full unroll
  }

  float tot0 = (res4[0][0] + res4[0][1]) + (res4[0][2] + res4[0][3]);
  float tot1 = (res4[1][0] + res4[1][1]) + (res4[1][2] + res4[1][3]);
  float tot2 = (res4[2][0] + res4[2][1]) + (res4[2][2] + res4[2][3]);
#pragma unroll
  for (int off = 32; off >= 1; off >>= 1) {
    tot0 += __shfl_xor(tot0, off, 64);
    tot1 += __shfl_xor(tot1, off, 64);
    tot2 += __shfl_xor(tot2, off, 64);
  }
  if (lane == 0) {
    out[yi * 96 + xi0 + 0] = tot0 / (512.0f * nI0);
    out[yi * 96 + xi0 + 1] = tot1 / (512.0f * nI1);
    out[yi * 96 + xi0 + 2] = tot2 / (512.0f * nI2);
  }
}

// ---------------------------------------------------------------------------
extern "C" void kernel_launch(void* const* d_in, const int* in_sizes, int n_in,
                              void* d_out, int out_size, void* d_ws, size_t ws_size,
                              hipStream_t stream) {
  const float* x     = (const float*)d_in[0]; // [96,48,512]
  const float* y     = (const float*)d_in[1]; // [96,64,64]
  const float* nItem = (const float*)d_in[2]; // [96]
  const float* Wp    = (const float*)d_in[3]; // [512,64]
  const float* W1    = (const float*)d_in[4]; // [64,128]
  const float* W2    = (const float*)d_in[5]; // [2,1]
  float* out = (float*)d_out;                 // [96,96,1]

  unsigned short* pyf = (unsigned short*)d_ws;   // 786432 u16 (1.5MB)
  unsigned short* pxf = pyf + 786432;            // 589824 u16 (1.125MB)

  hipLaunchKernelGGL(k_prep3, dim3(336), dim3(256), 0, stream, x, y, Wp, W1, pyf, pxf);
  hipLaunchKernelGGL(k_att, dim3(768), dim3(256), 0, stream, pyf, pxf, nItem, W2, out);
}

// Round 11
// 37.429 us; speedup vs baseline: 1.2950x; 1.2950x over previous
//
#include <hip/hip_runtime.h>
#include <hip/hip_bf16.h>

// ---------------------------------------------------------------------------
// scores[y,x] = sum_h W2[h] * ( sum_{m,n} leaky( py[y,h,m,:].px[x,h,n,:] /8 ) ) / (nItem[x]*64)
// r10 finding: prep was ~27-40us of every round (att only ~5-8us), and it's
// latency-bound on BARRIER-PHASED LDS staging at ~1 wave/SIMD, not on math.
// Fix: barrier-free prep. 3 nodes:
//   k_wprep (160 blk): Wp/W1 -> bf16 MFMA-frag images in global (96KB).
//   k_prep4 (168 blk x 4 INDEPENDENT waves, zero __syncthreads):
//     px wave (wid<288): 16 x-rows. GEMM1 streams WpF frags from L2 (64 b128),
//       gelu, private per-wave gal LDS slice (same-wave RAW, no barrier —
//       validated r3/r5/r7), GEMM2 streams W1F, scatter pxf frags.
//     py wave (wid>=288): 16 y-rows. 16 MFMA with W1F, scatter pyf frags.
//   k_att (768 blk, r6 verbatim, measured ~5-8us): wave = 1 yi x 3 xi,
//     A-frags register-resident, B prefetch-pipelined, leaky folded into FMAs.
// Fragment map (A and B of mfma_f32_16x16x32_bf16, same map):
//   lane l holds (rc=l&15, k=8*(l>>4)+i), i=0..7.  C/D: col=l&15, row=(l>>4)*4+j.
// py image: [y][h][mt(4)][kc(2)][lane(64)][i(8)]
// px image: [x][h][nt(3)][kc(2)][lane(64)][i(8)]
// WpF image: [kc(16)][nt(4)][lane][8]   W1F image: [kc(2)][nt(8)][lane][8]
// ---------------------------------------------------------------------------

typedef short bf16x8 __attribute__((ext_vector_type(8)));
typedef float f32x4 __attribute__((ext_vector_type(4)));

__device__ __forceinline__ unsigned short f2bf(float v) {
  __hip_bfloat16 b = __float2bfloat16(v);
  return *reinterpret_cast<unsigned short*>(&b);
}

__device__ __forceinline__ bf16x8 load8_cvt(const float* __restrict__ p) {
  f32x4 v0 = *reinterpret_cast<const f32x4*>(p);
  f32x4 v1 = *reinterpret_cast<const f32x4*>(p + 4);
  bf16x8 r;
  r[0] = (short)f2bf(v0[0]); r[1] = (short)f2bf(v0[1]);
  r[2] = (short)f2bf(v0[2]); r[3] = (short)f2bf(v0[3]);
  r[4] = (short)f2bf(v1[0]); r[5] = (short)f2bf(v1[1]);
  r[6] = (short)f2bf(v1[2]); r[7] = (short)f2bf(v1[3]);
  return r;
}

// ---------------------------------------------------------------------------
// node1: weight frag images (verified r1/r2).
// ---------------------------------------------------------------------------
__global__ __launch_bounds__(256) void k_wprep(const float* __restrict__ Wp,
                                               const float* __restrict__ W1,
                                               unsigned short* __restrict__ WpF,
                                               unsigned short* __restrict__ W1F) {
  int tid = blockIdx.x * 256 + threadIdx.x;
  if (tid < 32768) {
    int kc = tid >> 11, nt = (tid >> 9) & 3, l = (tid >> 3) & 63, i = tid & 7;
    int k = 32 * kc + 8 * (l >> 4) + i, c = nt * 16 + (l & 15);
    WpF[tid] = f2bf(Wp[k * 64 + c]);
  } else {
    int t2 = tid - 32768;
    int kc = t2 >> 12, nt = (t2 >> 9) & 7, l = (t2 >> 3) & 63, i = t2 & 7;
    int k = 32 * kc + 8 * (l >> 4) + i, d = nt * 16 + (l & 15);
    W1F[t2] = f2bf(W1[k * 128 + d]);
  }
}

// ---------------------------------------------------------------------------
// node2: barrier-free frag production. 168 blocks x 4 independent waves.
// LDS: 4 private gal slices (16x72 u16) = 9KB/block.
// ---------------------------------------------------------------------------
__global__ __launch_bounds__(256) void k_prep4(const float* __restrict__ x,
                                               const float* __restrict__ y,
                                               const unsigned short* __restrict__ WpF_u,
                                               const unsigned short* __restrict__ W1F_u,
                                               unsigned short* __restrict__ pyf,
                                               unsigned short* __restrict__ pxf) {
  __shared__ unsigned short gal[4][1152];   // per-wave 16x72 (padded)
  int lane = threadIdx.x & 63, w = threadIdx.x >> 6;
  int wid = blockIdx.x * 4 + w;             // global wave id, 0..671
  const bf16x8* WPF = reinterpret_cast<const bf16x8*>(WpF_u);
  const bf16x8* W1F = reinterpret_cast<const bf16x8*>(W1F_u);

  f32x4 zero4 = {0.f, 0.f, 0.f, 0.f};
  asm volatile("" : "+v"(zero4));           // pin zero C-operand

  if (wid < 288) {
    // ========================= px wave: 16 x-rows =========================
    int rowbase = wid * 16;
    const float* xa = x + (size_t)(rowbase + (lane & 15)) * 512 + 8 * (lane >> 4);
    f32x4 acc[4];
#pragma unroll
    for (int nt = 0; nt < 4; ++nt) acc[nt] = (f32x4){0.f, 0.f, 0.f, 0.f};
#pragma unroll
    for (int kc = 0; kc < 16; ++kc) {
      bf16x8 a = load8_cvt(xa + 32 * kc);
#pragma unroll
      for (int nt = 0; nt < 4; ++nt)
        acc[nt] = __builtin_amdgcn_mfma_f32_16x16x32_bf16(a, WPF[(kc * 4 + nt) * 64 + lane], acc[nt], 0, 0, 0);
    }
    // gelu -> private gal slice (same-wave LDS RAW; no barrier)
#pragma unroll
    for (int nt = 0; nt < 4; ++nt)
#pragma unroll
      for (int j = 0; j < 4; ++j) {
        float s = acc[nt][j];
        float ge = 0.5f * s * (1.0f + erff(s * 0.70710678118654752f));
        gal[w][((lane >> 4) * 4 + j) * 72 + nt * 16 + (lane & 15)] = f2bf(ge);
      }
    const unsigned short* gp = &gal[w][(lane & 15) * 72 + 8 * (lane >> 4)];
    bf16x8 g0 = *reinterpret_cast<const bf16x8*>(gp);
    bf16x8 g1 = *reinterpret_cast<const bf16x8*>(gp + 32);
#pragma unroll
    for (int nt2 = 0; nt2 < 8; ++nt2) {
      f32x4 acc2 = __builtin_amdgcn_mfma_f32_16x16x32_bf16(g0, W1F[nt2 * 64 + lane], zero4, 0, 0, 0);
      acc2 = __builtin_amdgcn_mfma_f32_16x16x32_bf16(g1, W1F[(8 + nt2) * 64 + lane], acc2, 0, 0, 0);
      int d = nt2 * 16 + (lane & 15);
      int h = d >> 6, dd = d & 63;
      int kc = dd >> 5, q2 = (dd >> 3) & 3, i = dd & 7;
#pragma unroll
      for (int j = 0; j < 4; ++j) {
        int row = rowbase + (lane >> 4) * 4 + j;
        int xi = row / 48, n = row % 48;
        int nt3 = n >> 4, rr = n & 15;
        size_t idx = ((size_t)((xi * 2 + h) * 6 + nt3 * 2 + kc)) * 512 + (rr + (q2 << 4)) * 8 + i;
        pxf[idx] = f2bf(acc2[j]);
      }
    }
  } else {
    // ========================= py wave: 16 y-rows =========================
    int row0 = (wid - 288) * 16;
    const float* ybp = y + (size_t)(row0 + (lane & 15)) * 64 + 8 * (lane >> 4);
    bf16x8 a0 = load8_cvt(ybp);
    bf16x8 a1 = load8_cvt(ybp + 32);
#pragma unroll
    for (int nt2 = 0; nt2 < 8; ++nt2) {
      f32x4 acc = __builtin_amdgcn_mfma_f32_16x16x32_bf16(a0, W1F[nt2 * 64 + lane], zero4, 0, 0, 0);
      acc = __builtin_amdgcn_mfma_f32_16x16x32_bf16(a1, W1F[(8 + nt2) * 64 + lane], acc, 0, 0, 0);
      int d = nt2 * 16 + (lane & 15);
      int h = d >> 6, dd = d & 63;
      int kc = dd >> 5, q2 = (dd >> 3) & 3, i = dd & 7;
#pragma unroll
      for (int j = 0; j < 4; ++j) {
        int row = row0 + (lane >> 4) * 4 + j;
        int yi = row >> 6, m = row & 63;
        int mt3 = m >> 4, rr = m & 15;
        size_t idx = ((size_t)((yi * 2 + h) * 8 + mt3 * 2 + kc)) * 512 + (rr + (q2 << 4)) * 8 + i;
        pyf[idx] = f2bf(acc[j]);
      }
    }
  }
}

// ---------------------------------------------------------------------------
// node3: pairwise att (r6 verbatim — the control). 768 blocks.
// ---------------------------------------------------------------------------
__global__ __launch_bounds__(256) void k_att(const unsigned short* __restrict__ pyf_u,
                                             const unsigned short* __restrict__ pxf_u,
                                             const float* __restrict__ nItem,
                                             const float* __restrict__ W2,
                                             float* __restrict__ out) {
  int lane = threadIdx.x & 63;
  int w = threadIdx.x >> 6;
  int bid = blockIdx.x;
  int yb = bid >> 5, xq = bid & 31;
  int yi = yb * 4 + w;
  int xi0 = xq * 3;
  const bf16x8* PA = reinterpret_cast<const bf16x8*>(pyf_u);
  const bf16x8* PB = reinterpret_cast<const bf16x8*>(pxf_u);

  float w2h0 = W2[0], w2h1 = W2[1];
  float nI0 = nItem[xi0], nI1 = nItem[xi0 + 1], nI2 = nItem[xi0 + 2];

  f32x4 zero4 = {0.f, 0.f, 0.f, 0.f};
  asm volatile("" : "+v"(zero4));

  bf16x8 A8[16];                           // both heads: [h*8 + mt*2 + kc]
  size_t abase = (size_t)(yi * 2) * 512 + lane;
#pragma unroll
  for (int f = 0; f < 8; ++f) {
    A8[f]     = PA[abase + f * 64];
    A8[8 + f] = PA[abase + 512 + f * 64];
  }
  float c3h0 = 0.3f * w2h0, c7h0 = 0.7f * w2h0;
  float c3h1 = 0.3f * w2h1, c7h1 = 0.7f * w2h1;

  bf16x8 Bc[6], Bn[6];
  size_t bb0 = (size_t)((xi0 * 2 + 0) * 6) * 64 + lane;  // s=0: g=0,h=0
#pragma unroll
  for (int f = 0; f < 6; ++f) Bc[f] = PB[bb0 + f * 64];

  f32x4 res4[3];
#pragma unroll
  for (int g = 0; g < 3; ++g) res4[g] = (f32x4){0.f, 0.f, 0.f, 0.f};

#pragma unroll
  for (int s = 0; s < 6; ++s) {
    const int h = s / 3, g = s % 3;
    if (s < 5) {                            // prefetch next step's B-frags
      const int s2 = s + 1, h2 = s2 / 3, g2 = s2 % 3;
      size_t bb = (size_t)(((xi0 + g2) * 2 + h2) * 6) * 64 + lane;
#pragma unroll
      for (int f = 0; f < 6; ++f) Bn[f] = PB[bb + f * 64];
    }
    const float c3 = h ? c3h1 : c3h0;
    const float c7 = h ? c7h1 : c7h0;
#pragma unroll
    for (int nt = 0; nt < 3; ++nt)
#pragma unroll
      for (int mt = 0; mt < 4; ++mt) {
        f32x4 acc = __builtin_amdgcn_mfma_f32_16x16x32_bf16(A8[h * 8 + mt * 2], Bc[nt * 2], zero4, 0, 0, 0);
        acc = __builtin_amdgcn_mfma_f32_16x16x32_bf16(A8[h * 8 + mt * 2 + 1], Bc[nt * 2 + 1], acc, 0, 0, 0);
        f32x4 mx = {fmaxf(acc[0], 0.f), fmaxf(acc[1], 0.f), fmaxf(acc[2], 0.f), fmaxf(acc[3], 0.f)};
        res4[g] += acc * c3;
        res4[g] += mx * c7;
      }
#pragma unroll
    for (int f = 0; f < 6; ++f) Bc[f] = Bn[f];  // renamed away by full unroll
  }

  float tot0 = (res4[0][0] + res4[0][1]) + (res4[0][2] + res4[0][3]);
  float tot1 = (res4[1][0] + res4[1][1]) + (res4[1][2] + res4[1][3]);
  float tot2 = (res4[2][0] + res4[2][1]) + (res4[2][2] + res4[2][3]);
#pragma unroll
  for (int off = 32; off >= 1; off >>= 1) {
    tot0 += __shfl_xor(tot0, off, 64);
    tot1 += __shfl_xor(tot1, off, 64);
    tot2 += __shfl_xor(tot2, off, 64);
  }
  if (lane == 0) {
    out[yi * 96 + xi0 + 0] = tot0 / (512.0f * nI0);
    out[yi * 96 + xi0 + 1] = tot1 / (512.0f * nI1);
    out[yi * 96 + xi0 + 2] = tot2 / (512.0f * nI2);
  }
}

// ---------------------------------------------------------------------------
extern "C" void kernel_launch(void* const* d_in, const int* in_sizes, int n_in,
                              void* d_out, int out_size, void* d_ws, size_t ws_size,
                              hipStream_t stream) {
  const float* x     = (const float*)d_in[0]; // [96,48,512]
  const float* y     = (const float*)d_in[1]; // [96,64,64]
  const float* nItem = (const float*)d_in[2]; // [96]
  const float* Wp    = (const float*)d_in[3]; // [512,64]
  const float* W1    = (const float*)d_in[4]; // [64,128]
  const float* W2    = (const float*)d_in[5]; // [2,1]
  float* out = (float*)d_out;                 // [96,96,1]

  unsigned short* WpF = (unsigned short*)d_ws;   // 32768 u16 (64KB)
  unsigned short* W1F = WpF + 32768;             // 8192 u16 (16KB)
  unsigned short* pyf = W1F + 8192;              // 786432 u16 (1.5MB)
  unsigned short* pxf = pyf + 786432;            // 589824 u16 (1.125MB)

  hipLaunchKernelGGL(k_wprep, dim3(160), dim3(256), 0, stream, Wp, W1, WpF, W1F);
  hipLaunchKernelGGL(k_prep4, dim3(168), dim3(256), 0, stream, x, y, WpF, W1F, pyf, pxf);
  hipLaunchKernelGGL(k_att, dim3(768), dim3(256), 0, stream, pyf, pxf, nItem, W2, out);
}